// Round 12
// baseline (192.689 us; speedup 1.0000x reference)
//
#include <hip/hip_runtime.h>

// Problem constants (fixed by setup_inputs)
#define NNODES 50000
#define NEDGES 800000
#define DIM    128
#define NRELS  4          // edge relations; weight slice 4 = self-loop
#define DBLK   128        // k_dfill dense blocks per rel (r2 mapping)
#define NDB    (4*DBLK)   // 512 dense blocks (self-loop lives in k_agg)
#define NFB    3125       // fill blocks
#define EPB    12500      // edges per hist chunk
#define NHC    64         // hist chunks (NHC*EPB == NEDGES)
#define RNG    12500      // dst bins per hist range-block (4 ranges cover NNODES)
#define SCB    200        // scan blocks (200*256 = 51200 bins)

typedef __attribute__((ext_vector_type(8))) short bf16x8;
typedef __attribute__((ext_vector_type(8))) unsigned short u16x8;
typedef __attribute__((ext_vector_type(4))) float f32x4;

// ---- ws layout (bytes) ----
#define SSRC_OFF 0             // u32[NEDGES]: rowcode = rel*NNODES+src, dst-sorted  3,200,000
#define CNT_OFF  3200000       // u32[51200] dst histogram excl scan                   204,800
#define BSUM_OFF 3404800       // u32[200] publish array + u32 flag at +800             1,024
#define RANK_OFF 3405824       // u16[NEDGES] within-(chunk,dst) rank                1,600,000
#define PCNT_OFF 5005824       // u16[NHC][NNODES] per-chunk hist -> excl col-scan   6,400,000
#define WT_OFF   11405824      // bf16[5*128*128] W^T                                  163,840
#define XBF_OFF  11569664      // bf16[NNODES*DIM]                                  12,800,000
#define H_OFF    24369664      // bf16[4*NNODES*128] per-rel transforms             51,200,000
                               // total ~75.6 MB

__device__ __forceinline__ unsigned short f2bf(float f) {  // RNE f32->bf16
  unsigned u = __float_as_uint(f);
  return (unsigned short)((u + 0x7FFFu + ((u >> 16) & 1u)) >> 16);
}

// ---- convert: x f32->bf16, W transpose+convert. Pure streaming, no LDS, full
// occupancy (r12: split from the fused k_ph for per-dispatch visibility -- the
// pipeline has ~80us unaccounted outside the two 46us kernels).
__global__ __launch_bounds__(256) void k_conv(
    const float* __restrict__ x, unsigned short* __restrict__ xbf,
    const float* __restrict__ W, unsigned short* __restrict__ Wt, unsigned* flag) {
  int i = blockIdx.x * 256 + threadIdx.x;
  if (i == 0) atomicExch(flag, 0u);  // reset k_scan's barrier flag
  if (i < NNODES * DIM / 8) {
    const float4* p = (const float4*)x + i * 2;
    float4 v0 = p[0], v1 = p[1];
    u16x8 o;
    o[0] = f2bf(v0.x); o[1] = f2bf(v0.y); o[2] = f2bf(v0.z); o[3] = f2bf(v0.w);
    o[4] = f2bf(v1.x); o[5] = f2bf(v1.y); o[6] = f2bf(v1.z); o[7] = f2bf(v1.w);
    *(u16x8*)(xbf + i * 8) = o;
  }
  if (i < 5 * DIM * DIM) {
    int r = i >> 14, rem = i & 16383, k = rem >> 7, c = rem & 127;
    Wt[(r << 14) + (c << 7) + k] = f2bf(W[i]);
  }
}

// ---- LDS-privatized per-chunk dst histogram + within-chunk rank (no global
// atomics). r12: 64 chunks x 4 dst-ranges = 256 blocks (was 128 = half the GPU
// idle), 512 threads, 12500 bins/range packed 2 x u16 per u32 = 25KB LDS; low
// field max 12500 so the packed add never carries. pcnt layout unchanged: the 4
// ranges tile each u16[NNODES] row exactly.
__global__ __launch_bounds__(512) void k_hist(const int* __restrict__ dst,
                                              unsigned short* __restrict__ rank,
                                              unsigned short* __restrict__ pcnt) {
  __shared__ unsigned lh[RNG / 2];  // 6250 u32 = 25,000 B
  int c = blockIdx.x >> 2;
  int r0 = (blockIdx.x & 3) * RNG;
  for (int i = threadIdx.x; i < RNG / 2; i += 512) lh[i] = 0u;
  __syncthreads();
  int e0 = c * EPB;
  for (int e = e0 + threadIdx.x; e < e0 + EPB; e += 512) {
    int d = dst[e] - r0;
    if ((unsigned)d < (unsigned)RNG) {
      unsigned old = atomicAdd(&lh[d >> 1], (d & 1) ? 65536u : 1u);
      rank[e] = (unsigned short)((old >> ((d & 1) << 4)) & 0xFFFFu);
    }
  }
  __syncthreads();
  // dump packed u16 pairs: exactly the u16[RNG] slice of row c at offset r0
  unsigned* prow = (unsigned*)(pcnt + (size_t)c * NNODES + r0);
  for (int i = threadIdx.x; i < RNG / 2; i += 512) prow[i] = lh[i];
}

// ---- FUSED scan (scanC + scanA + k_fix in one dispatch).
// One bin per thread. Pass 1: column-scan over the NHC chunk rows in place ->
// per-chunk exclusive prefix; run = bin total. Pass 2: in-block exclusive scan of
// the 256 bin totals. Pass 3: publish block total via device-scope atomics, ALL
// blocks publish BEFORE spinning (200 blocks < 256 CUs: fully co-resident), then
// parallel-reduce the preceding block totals -> global exclusive prefix -> cnt[d].
__global__ __launch_bounds__(256) void k_scan(unsigned short* __restrict__ pcnt,
                                              unsigned* __restrict__ cnt,
                                              unsigned* bsum, unsigned* flag) {
  __shared__ unsigned sh[256];
  int tid = threadIdx.x, blk = blockIdx.x;
  int d = blk * 256 + tid;  // 200*256 = 51200 exact
  unsigned run = 0;
  if (d < NNODES) {
#pragma unroll 8
    for (int b = 0; b < NHC; b++) {
      size_t off = (size_t)b * NNODES + d;
      unsigned v = pcnt[off];
      pcnt[off] = (unsigned short)run;
      run += v;
    }
  }
  sh[tid] = run;
  __syncthreads();
  for (int off = 1; off < 256; off <<= 1) {
    unsigned t = (tid >= off) ? sh[tid - off] : 0u;
    __syncthreads();
    sh[tid] += t;
    __syncthreads();
  }
  unsigned excl = sh[tid] - run;  // in-block exclusive prefix of bin totals
  unsigned btot = sh[255];        // block total
  __syncthreads();                // sh reused below
  if (tid == 0) {
    atomicExch(&bsum[blk], btot);   // device-scope publish (cross-XCD coherent)
    atomicAdd(flag, 1u);
    while (atomicAdd(flag, 0u) < SCB) { __builtin_amdgcn_s_sleep(8); }
  }
  __syncthreads();
  unsigned pv = (tid < blk) ? atomicAdd(&bsum[tid], 0u) : 0u;  // coherent read
  sh[tid] = pv;
  __syncthreads();
  for (int off = 128; off > 0; off >>= 1) {
    if (tid < off) sh[tid] += sh[tid + off];
    __syncthreads();
  }
  cnt[d] = sh[0] + excl;  // global exclusive prefix (zero bins >= NNODES included)
}

// ---- FUSED dense + fill (r2 mapping: dense blocks [0,NDB) then fill blocks):
// Dense (rels 0..3 only; self-loop lives in k_agg): H[r][n]=xbf[n]@W_r+b_r
// (bf16, LDS-staged cached stores). Fill: scatter edge rowcodes into dst-sorted
// ssrc via pos = cnt[d] + chunk_prefix[e/EPB][d] + rank[e]. No atomics.
// launch_bounds MUST stay (256,2): the dense body holds B[8][4] (~128 VGPR of
// fragments); (256,4) capped VGPR at 64 and spilled (r7: FETCH +30MB, dur 48->63).
__global__ __launch_bounds__(256, 2) void k_dfill(
    const unsigned short* __restrict__ xbf, const unsigned short* __restrict__ Wt,
    const float* __restrict__ bias, unsigned short* __restrict__ H,
    const int* __restrict__ rel, const int* __restrict__ dst,
    const int* __restrict__ src, const unsigned* __restrict__ cnt,
    const unsigned short* __restrict__ rank, const unsigned short* __restrict__ pfx,
    unsigned* __restrict__ ssrc) {
  if (blockIdx.x >= NDB) {
    // ---- fill part: pure streaming, no atomics ----
    int e = (blockIdx.x - NDB) * 256 + threadIdx.x;
    if (e < NEDGES) {
      int r = rel[e]; r = r < 0 ? 0 : (r > NRELS - 1 ? NRELS - 1 : r);
      int d = dst[e];
      unsigned pos = cnt[d] + (unsigned)pfx[(size_t)(e / EPB) * NNODES + d] + (unsigned)rank[e];
      ssrc[pos] = (unsigned)(r * NNODES + src[e]);
    }
    return;
  }
  // ---- dense part ----
  __shared__ unsigned short st[4][2048];  // 4 waves x 4 KB tile staging
  int lane = threadIdx.x & 63;
  int wv = threadIdx.x >> 6;
  int r = blockIdx.x / DBLK;              // rel region 0..3
  const int NT = NNODES / 16;             // 3125 row-tiles per rel
  int col = lane & 15, quad = lane >> 4;

  const unsigned short* wr = Wt + (r << 14);
  bf16x8 B[8][4];
  float bs[8];
#pragma unroll
  for (int ct = 0; ct < 8; ct++) {
#pragma unroll
    for (int kk = 0; kk < 4; kk++)
      B[ct][kk] = *(const bf16x8*)(wr + ((ct * 16 + col) << 7) + kk * 32 + quad * 8);
    bs[ct] = bias[(r << 7) + ct * 16 + col];
  }

  for (int t = (blockIdx.x % DBLK) * 4 + wv; t < NT; t += DBLK * 4) {
    int n0 = t * 16;
    int na = n0 + col;
    bf16x8 a0 = *(const bf16x8*)(xbf + (na << 7) + quad * 8);
    bf16x8 a1 = *(const bf16x8*)(xbf + (na << 7) + 32 + quad * 8);
    bf16x8 a2 = *(const bf16x8*)(xbf + (na << 7) + 64 + quad * 8);
    bf16x8 a3 = *(const bf16x8*)(xbf + (na << 7) + 96 + quad * 8);

#pragma unroll
    for (int ct = 0; ct < 8; ct++) {
      f32x4 acc = {0.f, 0.f, 0.f, 0.f};
      acc = __builtin_amdgcn_mfma_f32_16x16x32_bf16(a0, B[ct][0], acc, 0, 0, 0);
      acc = __builtin_amdgcn_mfma_f32_16x16x32_bf16(a1, B[ct][1], acc, 0, 0, 0);
      acc = __builtin_amdgcn_mfma_f32_16x16x32_bf16(a2, B[ct][2], acc, 0, 0, 0);
      acc = __builtin_amdgcn_mfma_f32_16x16x32_bf16(a3, B[ct][3], acc, 0, 0, 0);
      int cc = ct * 16 + col;
#pragma unroll
      for (int j = 0; j < 4; j++) st[wv][(quad * 4 + j) * 128 + cc] = f2bf(acc[j] + bs[ct]);
    }
    // wave-private LDS round-trip (intra-wave lgkmcnt ordering; no __syncthreads)
    unsigned short* gb = H + (((size_t)(r * NNODES + n0)) << 7);
#pragma unroll
    for (int s = 0; s < 4; s++) {
      int off = s * 512 + lane * 8;  // u16 units: 4 bursts of 1KB, 16B/lane
      *(u16x8*)(gb + off) = *(const u16x8*)(&st[wv][off]);
    }
  }
}

// ---- segment-max + self-loop GEMM, fused; single write of out (no RMW).
// Phase 1: quarter-wave (16 lanes) per node gathers H rows (uint4/lane), 8-row
// clamped batches (max idempotent -> duplicates harmless, L2-hot); result (or 0
// for deg==0) to LDS smax. Structural note (r8-r11): occupancy/MLP/launch knobs
// all null -- k_agg is bound by L2-fill traffic of random 256B gathers (FETCH
// ~103MB at ~2.9 TB/s effective).
// Phase 2: the block's 16 nodes form one 16x128 @ 128x128 self-loop MFMA tile;
// epilogue adds bias + smax and stores out once, nontemporally (out not re-read).
__global__ __launch_bounds__(256, 8) void k_agg(
    const unsigned* __restrict__ cnt, const unsigned* __restrict__ ssrc,
    const uint4* __restrict__ H4, const unsigned short* __restrict__ xbf,
    const unsigned short* __restrict__ Wt, const float* __restrict__ bias,
    float* __restrict__ out) {
  __shared__ float smax[16][128];  // 8 KB
  int tid = threadIdx.x;
  int n0 = blockIdx.x * 16;        // grid 3125*16 = 50000 exact

  // ---- phase 1: max-gather ----
  int lane16 = tid & 15;
  int q = tid >> 4;
  int n = n0 + q;
  unsigned base = cnt[n];
  int deg = (int)(cnt[n + 1] - base);
  float init = (deg > 0) ? -3.0e38f : 0.0f;  // deg==0: DGL zero-fill
  float m0 = init, m1 = init, m2 = init, m3 = init;
  float m4 = init, m5 = init, m6 = init, m7 = init;
#define UNP(v)                                          \
  m0 = fmaxf(m0, __uint_as_float((v).x << 16));         \
  m1 = fmaxf(m1, __uint_as_float((v).x & 0xFFFF0000u)); \
  m2 = fmaxf(m2, __uint_as_float((v).y << 16));         \
  m3 = fmaxf(m3, __uint_as_float((v).y & 0xFFFF0000u)); \
  m4 = fmaxf(m4, __uint_as_float((v).z << 16));         \
  m5 = fmaxf(m5, __uint_as_float((v).z & 0xFFFF0000u)); \
  m6 = fmaxf(m6, __uint_as_float((v).w << 16));         \
  m7 = fmaxf(m7, __uint_as_float((v).w & 0xFFFF0000u))
  if (deg > 0) {
    int lim = deg - 1;
    for (int i = 0; i < deg; i += 8) {
      unsigned c0 = ssrc[base + min(i, lim)];
      unsigned c1 = ssrc[base + min(i + 1, lim)];
      unsigned c2 = ssrc[base + min(i + 2, lim)];
      unsigned c3 = ssrc[base + min(i + 3, lim)];
      unsigned c4 = ssrc[base + min(i + 4, lim)];
      unsigned c5 = ssrc[base + min(i + 5, lim)];
      unsigned c6 = ssrc[base + min(i + 6, lim)];
      unsigned c7 = ssrc[base + min(i + 7, lim)];
      uint4 v0 = H4[((size_t)c0 << 4) + lane16];
      uint4 v1 = H4[((size_t)c1 << 4) + lane16];
      uint4 v2 = H4[((size_t)c2 << 4) + lane16];
      uint4 v3 = H4[((size_t)c3 << 4) + lane16];
      uint4 v4 = H4[((size_t)c4 << 4) + lane16];
      uint4 v5 = H4[((size_t)c5 << 4) + lane16];
      uint4 v6 = H4[((size_t)c6 << 4) + lane16];
      uint4 v7 = H4[((size_t)c7 << 4) + lane16];
      UNP(v0); UNP(v1); UNP(v2); UNP(v3);
      UNP(v4); UNP(v5); UNP(v6); UNP(v7);
    }
  }
#undef UNP
  float4* sp = (float4*)&smax[q][lane16 * 8];
  sp[0] = (float4){m0, m1, m2, m3};
  sp[1] = (float4){m4, m5, m6, m7};
  __syncthreads();

  // ---- phase 2: self-loop 16x128 @ 128x128 + combine ----
  int l64 = tid & 63;
  int wv = tid >> 6;
  int col = l64 & 15, quad = l64 >> 4;
  const unsigned short* wr = Wt + (4 << 14);
  int na = n0 + col;
  bf16x8 a0 = *(const bf16x8*)(xbf + (na << 7) + quad * 8);
  bf16x8 a1 = *(const bf16x8*)(xbf + (na << 7) + 32 + quad * 8);
  bf16x8 a2 = *(const bf16x8*)(xbf + (na << 7) + 64 + quad * 8);
  bf16x8 a3 = *(const bf16x8*)(xbf + (na << 7) + 96 + quad * 8);
#pragma unroll
  for (int cti = 0; cti < 2; cti++) {
    int ct = wv * 2 + cti;  // wave wv owns col-tiles 2wv, 2wv+1
    bf16x8 b0 = *(const bf16x8*)(wr + ((ct * 16 + col) << 7) + 0 * 32 + quad * 8);
    bf16x8 b1 = *(const bf16x8*)(wr + ((ct * 16 + col) << 7) + 1 * 32 + quad * 8);
    bf16x8 b2 = *(const bf16x8*)(wr + ((ct * 16 + col) << 7) + 2 * 32 + quad * 8);
    bf16x8 b3 = *(const bf16x8*)(wr + ((ct * 16 + col) << 7) + 3 * 32 + quad * 8);
    float bsv = bias[(4 << 7) + ct * 16 + col];
    f32x4 acc = {0.f, 0.f, 0.f, 0.f};
    acc = __builtin_amdgcn_mfma_f32_16x16x32_bf16(a0, b0, acc, 0, 0, 0);
    acc = __builtin_amdgcn_mfma_f32_16x16x32_bf16(a1, b1, acc, 0, 0, 0);
    acc = __builtin_amdgcn_mfma_f32_16x16x32_bf16(a2, b2, acc, 0, 0, 0);
    acc = __builtin_amdgcn_mfma_f32_16x16x32_bf16(a3, b3, acc, 0, 0, 0);
    int cc = ct * 16 + col;
#pragma unroll
    for (int j = 0; j < 4; j++) {
      int row = quad * 4 + j;
      __builtin_nontemporal_store(acc[j] + bsv + smax[row][cc],
                                  out + ((size_t)(n0 + row) << 7) + (unsigned)cc);
    }
  }
}

extern "C" void kernel_launch(void* const* d_in, const int* in_sizes, int n_in,
                              void* d_out, int out_size, void* d_ws, size_t ws_size,
                              hipStream_t stream) {
  const float* x = (const float*)d_in[0];
  const float* W = (const float*)d_in[1];
  const float* bias = (const float*)d_in[2];
  const int* src = (const int*)d_in[3];
  const int* dst = (const int*)d_in[4];
  const int* rel = (const int*)d_in[5];

  char* ws = (char*)d_ws;
  unsigned* ssrc = (unsigned*)(ws + SSRC_OFF);
  unsigned* cnt = (unsigned*)(ws + CNT_OFF);
  unsigned* bsum = (unsigned*)(ws + BSUM_OFF);
  unsigned* flag = (unsigned*)(ws + BSUM_OFF + 800);
  unsigned short* rank = (unsigned short*)(ws + RANK_OFF);
  unsigned short* pcnt = (unsigned short*)(ws + PCNT_OFF);
  unsigned short* Wt = (unsigned short*)(ws + WT_OFF);
  unsigned short* xbf = (unsigned short*)(ws + XBF_OFF);
  unsigned short* H = (unsigned short*)(ws + H_OFF);
  float* out = (float*)d_out;

  // 5 launches; r11 showed launch count is ~free, so we split conv/hist for
  // per-dispatch visibility into the ~80us unaccounted outside dfill+agg.
  hipLaunchKernelGGL(k_conv, dim3(3125), dim3(256), 0, stream, x, xbf, W, Wt, flag);
  hipLaunchKernelGGL(k_hist, dim3(NHC * 4), dim3(512), 0, stream, dst, rank, pcnt);
  hipLaunchKernelGGL(k_scan, dim3(SCB), dim3(256), 0, stream, pcnt, cnt, bsum, flag);
  hipLaunchKernelGGL(k_dfill, dim3(NDB + NFB), dim3(256), 0, stream, xbf, Wt, bias, H, rel,
                     dst, src, cnt, rank, pcnt, ssrc);
  hipLaunchKernelGGL(k_agg, dim3(3125), dim3(256), 0, stream, cnt, ssrc, (const uint4*)H, xbf,
                     Wt, bias, out);
}

// Round 13
// 180.768 us; speedup vs baseline: 1.0659x; 1.0659x over previous
//
#include <hip/hip_runtime.h>

// Problem constants (fixed by setup_inputs)
#define NNODES 50000
#define NEDGES 800000
#define DIM    128
#define NRELS  4          // edge relations; weight slice 4 = self-loop
#define DBLK   128        // k_dfill dense blocks per rel (r2 mapping)
#define NDB    (5*DBLK)   // 640 dense blocks (self-loop r=4 writes out directly)
#define NFB    3125       // fill blocks
#define EPB    12500      // edges per hist chunk
#define NHC    64         // hist chunks (NHC*EPB == NEDGES)
#define RNG    25000      // dst bins per hist range-block (2 ranges cover NNODES)
#define NPB    782        // prep blocks in k_ph (782*1024 >= 800000)
#define SCB    200        // scan blocks (200*256 = 51200 bins)

typedef __attribute__((ext_vector_type(8))) short bf16x8;
typedef __attribute__((ext_vector_type(8))) unsigned short u16x8;
typedef __attribute__((ext_vector_type(4))) float f32x4;

// ---- ws layout (bytes) ----
#define SSRC_OFF 0             // u32[NEDGES]: rowcode = rel*NNODES+src, dst-sorted  3,200,000
#define CNT_OFF  3200000       // u32[51200] dst histogram excl scan                   204,800
#define BSUM_OFF 3404800       // u32[200] publish array + u32 flag at +800             1,024
#define RANK_OFF 3405824       // u16[NEDGES] within-(chunk,dst) rank                1,600,000
#define PCNT_OFF 5005824       // u16[NHC][NNODES] per-chunk hist -> excl col-scan   6,400,000
#define WT_OFF   11405824      // bf16[5*128*128] W^T                                  163,840
#define XBF_OFF  11569664      // bf16[NNODES*DIM]                                  12,800,000
#define H_OFF    24369664      // bf16[4*NNODES*128] per-rel transforms             51,200,000
                               // total ~75.6 MB

__device__ __forceinline__ unsigned short f2bf(float f) {  // RNE f32->bf16
  unsigned u = __float_as_uint(f);
  return (unsigned short)((u + 0x7FFFu + ((u >> 16) & 1u)) >> 16);
}

// ---- FUSED prep + hist (independent roles, disjoint block ranges, co-scheduled):
// Blocks [0, NHC*2): LDS-privatized per-chunk dst histogram + within-chunk rank.
//   25000 bins/range packed 2 x u16 per u32 = 50KB LDS; low field max 12500 so the
//   packed add never carries across fields. No global atomics.
// Blocks [NHC*2, +NPB): x f32->bf16 convert, W transpose+convert (pure BW).
// Block 0 thread 0 also resets the k_scan barrier flag.
__global__ __launch_bounds__(1024) void k_ph(
    const float* __restrict__ x, unsigned short* __restrict__ xbf,
    const float* __restrict__ W, unsigned short* __restrict__ Wt,
    const int* __restrict__ dst, unsigned short* __restrict__ rank,
    unsigned short* __restrict__ pcnt, unsigned* flag) {
  __shared__ unsigned lh[RNG / 2];  // 12500 u32 = 50,000 B
  if (blockIdx.x < NHC * 2) {
    if (blockIdx.x == 0 && threadIdx.x == 0) atomicExch(flag, 0u);
    int c = blockIdx.x >> 1;
    int r0 = (blockIdx.x & 1) * RNG;
    for (int i = threadIdx.x; i < RNG / 2; i += 1024) lh[i] = 0u;
    __syncthreads();
    int e0 = c * EPB;
    for (int e = e0 + threadIdx.x; e < e0 + EPB; e += 1024) {
      int d = dst[e] - r0;
      if ((unsigned)d < (unsigned)RNG) {
        unsigned old = atomicAdd(&lh[d >> 1], (d & 1) ? 65536u : 1u);
        rank[e] = (unsigned short)((old >> ((d & 1) << 4)) & 0xFFFFu);
      }
    }
    __syncthreads();
    // dump packed u16 pairs: exactly the u16[RNG] slice of row c at offset r0
    unsigned* prow = (unsigned*)(pcnt + (size_t)c * NNODES + r0);
    for (int i = threadIdx.x; i < RNG / 2; i += 1024) prow[i] = lh[i];
    return;
  }
  int i = (blockIdx.x - NHC * 2) * 1024 + threadIdx.x;
  if (i < NNODES * DIM / 8) {
    const float4* p = (const float4*)x + i * 2;
    float4 v0 = p[0], v1 = p[1];
    u16x8 o;
    o[0] = f2bf(v0.x); o[1] = f2bf(v0.y); o[2] = f2bf(v0.z); o[3] = f2bf(v0.w);
    o[4] = f2bf(v1.x); o[5] = f2bf(v1.y); o[6] = f2bf(v1.z); o[7] = f2bf(v1.w);
    *(u16x8*)(xbf + i * 8) = o;
  }
  if (i < 5 * DIM * DIM) {
    int r = i >> 14, rem = i & 16383, k = rem >> 7, c = rem & 127;
    Wt[(r << 14) + (c << 7) + k] = f2bf(W[i]);
  }
}

// ---- FUSED scan on 200 blocks (r13: replaces r4's scanB, which ran 12.8MB of
// R+W on only 25 blocks = 25 CUs, a ~20-40us hidden serial phase; this spreads
// it over 200 CUs ~ 5us and folds the block-prefix fix in via a device barrier).
// One bin per thread. Pass 1: column-scan over the NHC chunk rows in place ->
// per-chunk exclusive prefix; run = bin total. Pass 2: in-block exclusive scan of
// the 256 bin totals. Pass 3: publish block total via device-scope atomics, ALL
// blocks publish BEFORE spinning (200 blocks < 256 CUs: co-residency guaranteed
// by capacity, no dispatch-order assumption), then parallel-reduce the preceding
// block totals -> global exclusive prefix -> cnt[d].
__global__ __launch_bounds__(256) void k_scan(unsigned short* __restrict__ pcnt,
                                              unsigned* __restrict__ cnt,
                                              unsigned* bsum, unsigned* flag) {
  __shared__ unsigned sh[256];
  int tid = threadIdx.x, blk = blockIdx.x;
  int d = blk * 256 + tid;  // 200*256 = 51200 exact
  unsigned run = 0;
  if (d < NNODES) {
#pragma unroll 8
    for (int b = 0; b < NHC; b++) {
      size_t off = (size_t)b * NNODES + d;
      unsigned v = pcnt[off];
      pcnt[off] = (unsigned short)run;
      run += v;
    }
  }
  sh[tid] = run;
  __syncthreads();
  for (int off = 1; off < 256; off <<= 1) {
    unsigned t = (tid >= off) ? sh[tid - off] : 0u;
    __syncthreads();
    sh[tid] += t;
    __syncthreads();
  }
  unsigned excl = sh[tid] - run;  // in-block exclusive prefix of bin totals
  unsigned btot = sh[255];        // block total
  __syncthreads();                // sh reused below
  if (tid == 0) {
    atomicExch(&bsum[blk], btot);   // device-scope publish (cross-XCD coherent)
    atomicAdd(flag, 1u);
    while (atomicAdd(flag, 0u) < SCB) { __builtin_amdgcn_s_sleep(8); }
  }
  __syncthreads();
  unsigned pv = (tid < blk) ? atomicAdd(&bsum[tid], 0u) : 0u;  // coherent read
  sh[tid] = pv;
  __syncthreads();
  for (int off = 128; off > 0; off >>= 1) {
    if (tid < off) sh[tid] += sh[tid + off];
    __syncthreads();
  }
  cnt[d] = sh[0] + excl;  // global exclusive prefix (zero bins >= NNODES included)
}

// ---- FUSED dense + fill (r2 mapping: dense blocks [0,NDB) then fill blocks):
// Dense: H[r][n]=xbf[n]@W_r+b_r (bf16, LDS-staged nontemporal stores); r==4 ->
// f32 out (self-loop, written directly; k_agg RMWs the max in).
// Fill: scatter edge rowcodes into dst-sorted ssrc via
// pos = cnt[d] + chunk_prefix[e/EPB][d] + rank[e]. No atomics anywhere.
// launch_bounds MUST stay (256,2): the dense body holds B[8][4] (~128 VGPR of
// fragments); (256,4) capped VGPR at 64 and spilled (r7: FETCH +30MB, dur 48->63).
__global__ __launch_bounds__(256, 2) void k_dfill(
    const unsigned short* __restrict__ xbf, const unsigned short* __restrict__ Wt,
    const float* __restrict__ bias, unsigned short* __restrict__ H,
    float* __restrict__ out, const int* __restrict__ rel, const int* __restrict__ dst,
    const int* __restrict__ src, const unsigned* __restrict__ cnt,
    const unsigned short* __restrict__ rank, const unsigned short* __restrict__ pfx,
    unsigned* __restrict__ ssrc) {
  if (blockIdx.x >= NDB) {
    // ---- fill part: pure streaming, no atomics ----
    int e = (blockIdx.x - NDB) * 256 + threadIdx.x;
    if (e < NEDGES) {
      int r = rel[e]; r = r < 0 ? 0 : (r > NRELS - 1 ? NRELS - 1 : r);
      int d = dst[e];
      unsigned pos = cnt[d] + (unsigned)pfx[(size_t)(e / EPB) * NNODES + d] + (unsigned)rank[e];
      ssrc[pos] = (unsigned)(r * NNODES + src[e]);
    }
    return;
  }
  // ---- dense part ----
  __shared__ unsigned short st[4][2048];  // 4 waves x 4 KB tile staging
  int lane = threadIdx.x & 63;
  int wv = threadIdx.x >> 6;
  int r = blockIdx.x / DBLK;              // rel region 0..4
  const int NT = NNODES / 16;             // 3125 row-tiles per rel
  int col = lane & 15, quad = lane >> 4;

  const unsigned short* wr = Wt + (r << 14);
  bf16x8 B[8][4];
  float bs[8];
#pragma unroll
  for (int ct = 0; ct < 8; ct++) {
#pragma unroll
    for (int kk = 0; kk < 4; kk++)
      B[ct][kk] = *(const bf16x8*)(wr + ((ct * 16 + col) << 7) + kk * 32 + quad * 8);
    bs[ct] = bias[(r << 7) + ct * 16 + col];
  }

  for (int t = (blockIdx.x % DBLK) * 4 + wv; t < NT; t += DBLK * 4) {
    int n0 = t * 16;
    int na = n0 + col;
    bf16x8 a0 = *(const bf16x8*)(xbf + (na << 7) + quad * 8);
    bf16x8 a1 = *(const bf16x8*)(xbf + (na << 7) + 32 + quad * 8);
    bf16x8 a2 = *(const bf16x8*)(xbf + (na << 7) + 64 + quad * 8);
    bf16x8 a3 = *(const bf16x8*)(xbf + (na << 7) + 96 + quad * 8);

    if (r < NRELS) {
#pragma unroll
      for (int ct = 0; ct < 8; ct++) {
        f32x4 acc = {0.f, 0.f, 0.f, 0.f};
        acc = __builtin_amdgcn_mfma_f32_16x16x32_bf16(a0, B[ct][0], acc, 0, 0, 0);
        acc = __builtin_amdgcn_mfma_f32_16x16x32_bf16(a1, B[ct][1], acc, 0, 0, 0);
        acc = __builtin_amdgcn_mfma_f32_16x16x32_bf16(a2, B[ct][2], acc, 0, 0, 0);
        acc = __builtin_amdgcn_mfma_f32_16x16x32_bf16(a3, B[ct][3], acc, 0, 0, 0);
        int cc = ct * 16 + col;
#pragma unroll
        for (int j = 0; j < 4; j++) st[wv][(quad * 4 + j) * 128 + cc] = f2bf(acc[j] + bs[ct]);
      }
      // wave-private LDS round-trip (intra-wave lgkmcnt ordering; no __syncthreads)
      unsigned short* gb = H + (((size_t)(r * NNODES + n0)) << 7);
#pragma unroll
      for (int s = 0; s < 4; s++) {
        int off = s * 512 + lane * 8;  // u16 units: 4 bursts of 1KB, 16B/lane
        __builtin_nontemporal_store(*(const u16x8*)(&st[wv][off]), (u16x8*)(gb + off));
      }
    } else {
#pragma unroll
      for (int ct = 0; ct < 8; ct++) {
        f32x4 acc = {0.f, 0.f, 0.f, 0.f};
        acc = __builtin_amdgcn_mfma_f32_16x16x32_bf16(a0, B[ct][0], acc, 0, 0, 0);
        acc = __builtin_amdgcn_mfma_f32_16x16x32_bf16(a1, B[ct][1], acc, 0, 0, 0);
        acc = __builtin_amdgcn_mfma_f32_16x16x32_bf16(a2, B[ct][2], acc, 0, 0, 0);
        acc = __builtin_amdgcn_mfma_f32_16x16x32_bf16(a3, B[ct][3], acc, 0, 0, 0);
        int cc = ct * 16 + col;
#pragma unroll
        for (int j = 0; j < 4; j++)
          __builtin_nontemporal_store(acc[j] + bs[ct],
                                      out + ((size_t)(n0 + quad * 4 + j) << 7) + (unsigned)cc);
      }
    }
  }
}

// ---- segment-max over H rows per dst node + combine into d_out (RMW) ----
// Quarter-wave (16 lanes) per node; each lane owns 8 cols (uint4 = 16B of the 256B
// bf16 row). 8-row clamped-index batches: max is idempotent, so out-of-range rows
// clamp to the last edge (duplicate max, harmless, L2-hot) -> constant 8 gathers
// in flight, no serial remainder. Structural note (r8-r12): occupancy/MLP/launch
// knobs all null -- bound by L2-fill of random 256B gathers (FETCH ~103MB = H x2
// cross-XCD duplication; reuse already fully captured by L2).
__global__ __launch_bounds__(256, 4) void k_agg(
    const unsigned* __restrict__ cnt, const unsigned* __restrict__ ssrc,
    const uint4* __restrict__ H4, float* __restrict__ out) {
  int lane = threadIdx.x & 15;
  int q = threadIdx.x >> 4;
  int n = blockIdx.x * 16 + q;            // grid 3125*16 = 50000 exact
  unsigned base = cnt[n];
  int deg = (int)(cnt[n + 1] - base);

  float m0 = -3.0e38f, m1 = -3.0e38f, m2 = -3.0e38f, m3 = -3.0e38f;
  float m4 = -3.0e38f, m5 = -3.0e38f, m6 = -3.0e38f, m7 = -3.0e38f;
#define UNP(v)                                          \
  m0 = fmaxf(m0, __uint_as_float((v).x << 16));         \
  m1 = fmaxf(m1, __uint_as_float((v).x & 0xFFFF0000u)); \
  m2 = fmaxf(m2, __uint_as_float((v).y << 16));         \
  m3 = fmaxf(m3, __uint_as_float((v).y & 0xFFFF0000u)); \
  m4 = fmaxf(m4, __uint_as_float((v).z << 16));         \
  m5 = fmaxf(m5, __uint_as_float((v).z & 0xFFFF0000u)); \
  m6 = fmaxf(m6, __uint_as_float((v).w << 16));         \
  m7 = fmaxf(m7, __uint_as_float((v).w & 0xFFFF0000u))
  if (deg > 0) {
    int lim = deg - 1;
    for (int i = 0; i < deg; i += 8) {
      unsigned c0 = ssrc[base + min(i, lim)];
      unsigned c1 = ssrc[base + min(i + 1, lim)];
      unsigned c2 = ssrc[base + min(i + 2, lim)];
      unsigned c3 = ssrc[base + min(i + 3, lim)];
      unsigned c4 = ssrc[base + min(i + 4, lim)];
      unsigned c5 = ssrc[base + min(i + 5, lim)];
      unsigned c6 = ssrc[base + min(i + 6, lim)];
      unsigned c7 = ssrc[base + min(i + 7, lim)];
      uint4 v0 = H4[((size_t)c0 << 4) + lane];
      uint4 v1 = H4[((size_t)c1 << 4) + lane];
      uint4 v2 = H4[((size_t)c2 << 4) + lane];
      uint4 v3 = H4[((size_t)c3 << 4) + lane];
      uint4 v4 = H4[((size_t)c4 << 4) + lane];
      uint4 v5 = H4[((size_t)c5 << 4) + lane];
      uint4 v6 = H4[((size_t)c6 << 4) + lane];
      uint4 v7 = H4[((size_t)c7 << 4) + lane];
      UNP(v0); UNP(v1); UNP(v2); UNP(v3);
      UNP(v4); UNP(v5); UNP(v6); UNP(v7);
    }
  }
#undef UNP
  float4* op = (float4*)(out + ((size_t)n << 7)) + lane * 2;
  float4 s0 = op[0], s1 = op[1];          // self-loop result from k_dfill
  if (deg > 0) {                          // deg==0: DGL zero-fill, add nothing
    s0.x += m0; s0.y += m1; s0.z += m2; s0.w += m3;
    s1.x += m4; s1.y += m5; s1.z += m6; s1.w += m7;
  }
  op[0] = s0; op[1] = s1;
}

extern "C" void kernel_launch(void* const* d_in, const int* in_sizes, int n_in,
                              void* d_out, int out_size, void* d_ws, size_t ws_size,
                              hipStream_t stream) {
  const float* x = (const float*)d_in[0];
  const float* W = (const float*)d_in[1];
  const float* bias = (const float*)d_in[2];
  const int* src = (const int*)d_in[3];
  const int* dst = (const int*)d_in[4];
  const int* rel = (const int*)d_in[5];

  char* ws = (char*)d_ws;
  unsigned* ssrc = (unsigned*)(ws + SSRC_OFF);
  unsigned* cnt = (unsigned*)(ws + CNT_OFF);
  unsigned* bsum = (unsigned*)(ws + BSUM_OFF);
  unsigned* flag = (unsigned*)(ws + BSUM_OFF + 800);
  unsigned short* rank = (unsigned short*)(ws + RANK_OFF);
  unsigned short* pcnt = (unsigned short*)(ws + PCNT_OFF);
  unsigned short* Wt = (unsigned short*)(ws + WT_OFF);
  unsigned short* xbf = (unsigned short*)(ws + XBF_OFF);
  unsigned short* H = (unsigned short*)(ws + H_OFF);
  float* out = (float*)d_out;

  // 4 launches: r4's best-measured structure + the 200-block fused scan.
  hipLaunchKernelGGL(k_ph, dim3(NHC * 2 + NPB), dim3(1024), 0, stream, x, xbf, W, Wt, dst, rank,
                     pcnt, flag);
  hipLaunchKernelGGL(k_scan, dim3(SCB), dim3(256), 0, stream, pcnt, cnt, bsum, flag);
  hipLaunchKernelGGL(k_dfill, dim3(NDB + NFB), dim3(256), 0, stream, xbf, Wt, bias, H, out, rel,
                     dst, src, cnt, rank, pcnt, ssrc);
  hipLaunchKernelGGL(k_agg, dim3(3125), dim3(256), 0, stream, cnt, ssrc, (const uint4*)H, out);
}